// Round 10
// baseline (408.321 us; speedup 1.0000x reference)
//
#include <hip/hip_runtime.h>
#include <hip/hip_bf16.h>
#include <hip/hip_fp16.h>
#include <math.h>

// Problem constants (fixed by reference)
#define BB   8
#define LL   512
#define DD   512
#define GG   8
#define SSS  4
#define FGC  4
#define FEC  64
#define EEC  32
#define DHC  256
#define RHC  256
#define NT   (BB*LL)   // 4096 tokens
#define TM   32        // tokens per expert tile
#define TR   4         // tokens per fused_route block

#define XC_STRIDE 264  // shorts per k8 group (32*8 + 8 pad)

typedef __attribute__((ext_vector_type(8))) short short8;
typedef __attribute__((ext_vector_type(4))) float floatx4;

__device__ __forceinline__ float gelu_exact(float x) {
    return 0.5f * x * (1.0f + erff(x * 0.70710678118654752440f));
}

// HW packed fp32->bf16 RNE; low 16 bits = first arg
__device__ __forceinline__ unsigned pk2(float a, float b) {
    union { __hip_bfloat162 h; unsigned u; } cv;
    cv.h = __float22bfloat162_rn(make_float2(a, b));
    return cv.u;
}
union U4S8 { unsigned u[4]; short8 s; };

__device__ __forceinline__ floatx4 mfma16(short8 a, short8 b, floatx4 c) {
    return __builtin_amdgcn_mfma_f32_16x16x32_bf16(a, b, c, 0, 0, 0);
}

// ---------------------------------------------------------------------------
// Prep: WinT[d][gs] = Win_h[g][d][s]; M2 = Wfe@Win_f fold; c2b = bias fold.
// ---------------------------------------------------------------------------
__global__ __launch_bounds__(256) void prep_kernel(
    const float* __restrict__ Win_h, const float* __restrict__ Win_f,
    const float* __restrict__ Wfe, const float* __restrict__ bfe,
    const float* __restrict__ bin_b,
    float* __restrict__ WinT, float* __restrict__ M2, float* __restrict__ c2b)
{
    const int tid = threadIdx.x;
    if (blockIdx.x < 64) {
        int idx = blockIdx.x * 256 + tid;      // d*32 + gs
        int d = idx >> 5, gs = idx & 31;
        int g = gs >> 2, s = gs & 3;
        WinT[idx] = Win_h[(size_t)g*DD*SSS + d*SSS + s];
    } else {
        if (tid < GG*FGC*SSS) {                // 128: (g,f,s)
            int g = tid >> 4, f = (tid >> 2) & 3, s = tid & 3;
            float acc = 0.f;
            for (int e = 0; e < FEC; ++e)
                acc += Wfe[(size_t)g*FGC*FEC + f*FEC + e] * Win_f[(size_t)g*FEC*SSS + e*SSS + s];
            M2[tid] = acc;
        } else if (tid < GG*FGC*SSS + GG*SSS) {  // 32: gs
            int gs = tid - GG*FGC*SSS;
            int g = gs >> 2, s = gs & 3;
            float acc = bin_b[gs];
            for (int e = 0; e < FEC; ++e)
                acc += bfe[g*FEC + e] * Win_f[(size_t)g*FEC*SSS + e*SSS + s];
            c2b[gs] = acc;
        }
    }
}

// ---------------------------------------------------------------------------
// Fused routing, TR=4 tokens/block (grid 1024). Appends (token, weight, slot
// ordinal) per selected expert; zeroes the mode-dependent accum target
// (zbuf, zn floats per token). fp32-exact topk as all passing rounds.
// ---------------------------------------------------------------------------
__global__ __launch_bounds__(256) void fused_route2(
    const float* __restrict__ hidden, const float* __restrict__ feat,
    const float* __restrict__ Wr1, const float* __restrict__ br1,
    const float* __restrict__ Wr2, const float* __restrict__ br2,
    const float* __restrict__ WinT, const float* __restrict__ M2,
    const float* __restrict__ c2b,
    int* __restrict__ bucket_tok, float* __restrict__ bucket_w,
    int* __restrict__ bucket_slot,
    int* __restrict__ counts,
    float* __restrict__ zbuf, int zn)
{
    const int t0  = blockIdx.x * TR;
    const int tid = threadIdx.x;

    __shared__ float hs[TR][DD];        // 8 KB
    __shared__ float ghs[TR][RHC+4];
    __shared__ float featb[TR][GG*FGC];
    __shared__ float part[256];
    __shared__ float glogb[TR][GG];
    __shared__ float gwvb[TR][GG];
    __shared__ float scoreb[TR][GG];
    __shared__ float ilogb[TR][GG*SSS];
    __shared__ float cwvb[TR][GG*SSS];

    for (int i = tid; i < TR*DD; i += 256) {
        int r = i >> 9, c = i & 511;
        hs[r][c] = hidden[(size_t)(t0 + r)*DD + c];
    }
    for (int i = tid; i < TR*zn; i += 256)   // zero accum target
        zbuf[(size_t)t0*zn + i] = 0.0f;
    if (tid < TR*GG*FGC) {   // 128
        int r = tid >> 5, c = tid & 31;
        featb[r][c] = feat[(t0 + r)*(GG*FGC) + c];
    }
    __syncthreads();

    if (tid < TR*GG) {       // score per (t,g)
        int t = tid >> 3, g = tid & 7;
        float s = 0.f;
        #pragma unroll
        for (int f = 0; f < FGC; ++f) s += fminf(fmaxf(featb[t][g*4+f], 0.f), 1.f);
        scoreb[t][g] = s * 0.25f;
    }

    // gh: thread owns Wr1 column h=tid for 4 tokens
    {
        float acc[TR];
        float b = br1[tid];
        #pragma unroll
        for (int t = 0; t < TR; ++t) acc[t] = b;
        #pragma unroll 2
        for (int k = 0; k < DD; k += 4) {
            float w0 = Wr1[(size_t)k*RHC + tid];
            float w1 = Wr1[(size_t)(k+1)*RHC + tid];
            float w2 = Wr1[(size_t)(k+2)*RHC + tid];
            float w3 = Wr1[(size_t)(k+3)*RHC + tid];
            #pragma unroll
            for (int t = 0; t < TR; ++t) {
                float4 h = *(const float4*)(&hs[t][k]);
                acc[t] += h.x*w0 + h.y*w1 + h.z*w2 + h.w*w3;
            }
        }
        #pragma unroll
        for (int t = 0; t < TR; ++t) ghs[t][tid] = gelu_exact(acc[t]);
    }
    __syncthreads();

    // glog: 32 threads (t,g)
    if (tid < TR*GG) {
        int t = tid >> 3, g = tid & 7;
        float s = br2[g];
        #pragma unroll 4
        for (int h = 0; h < RHC; ++h) s += ghs[t][h] * Wr2[h*GG + g];
        glogb[t][g] = s;
    }

    // ilog partials: all 256 threads = (t, gs, half-of-K)
    {
        const int t = tid >> 6, sub = tid & 63;
        const int gs = sub >> 1, half = sub & 1;
        float acc = 0.f;
        const int k0 = half*256;
        #pragma unroll 8
        for (int k = k0; k < k0 + 256; ++k) acc += hs[t][k] * WinT[k*32 + gs];
        part[tid] = acc;
    }
    __syncthreads();
    if (tid < TR*GG*SSS) {   // 128: (t,gs)
        const int t = tid >> 5, gs = tid & 31;
        const int g = gs >> 2, s = gs & 3;
        float acc = part[t*64 + gs*2] + part[t*64 + gs*2 + 1];
        const float* m2 = M2 + g*16 + s;     // stride 4 over f
        acc += featb[t][g*4+0]*m2[0] + featb[t][g*4+1]*m2[4]
             + featb[t][g*4+2]*m2[8] + featb[t][g*4+3]*m2[12];
        const float centers[4] = {0.0f, 1.0f/3.0f, 2.0f/3.0f, 1.0f};
        float diff = scoreb[t][g] - centers[s];
        ilogb[t][gs] = acc + c2b[gs] - 16.0f * diff * diff;
    }
    __syncthreads();

    // group top-2 softmax per token
    if (tid < TR) {
        int t = tid;
        float a = -INFINITY, b = -INFINITY;
        #pragma unroll
        for (int g = 0; g < GG; ++g) {
            float v = glogb[t][g];
            if (v > a) { b = a; a = v; } else if (v > b) { b = v; }
        }
        float thresh = b, m = a, sum = 0.f;
        float ex[GG];
        #pragma unroll
        for (int g = 0; g < GG; ++g) {
            float v = glogb[t][g];
            ex[g] = (v >= thresh) ? __expf(v - m) : 0.f;
            sum += ex[g];
        }
        float inv = 1.0f / sum;
        #pragma unroll
        for (int g = 0; g < GG; ++g) gwvb[t][g] = ex[g] * inv;
    }
    // stage top-2 softmax per (t,g)
    if (tid < TR*GG) {
        int t = tid >> 3, g = tid & 7;
        float vv[4] = {ilogb[t][g*4+0], ilogb[t][g*4+1], ilogb[t][g*4+2], ilogb[t][g*4+3]};
        float a = -INFINITY, b = -INFINITY;
        #pragma unroll
        for (int s = 0; s < 4; ++s) {
            float v = vv[s];
            if (v > a) { b = a; a = v; } else if (v > b) { b = v; }
        }
        float thresh = b, m = a, sum = 0.f;
        float ex[4];
        #pragma unroll
        for (int s = 0; s < 4; ++s) {
            ex[s] = (vv[s] >= thresh) ? __expf(vv[s] - m) : 0.f;
            sum += ex[s];
        }
        float inv = 1.0f / sum;
        #pragma unroll
        for (int s = 0; s < 4; ++s) cwvb[t][g*4 + s] = ex[s] * inv;
    }
    __syncthreads();

    if (tid < TR) {
        int t = tid, sc = 0;
        for (int g = 0; g < GG; ++g) {
            float gw = gwvb[t][g];
            if (gw > 0.f) {
                for (int s = 0; s < SSS; ++s) {
                    float w = gw * cwvb[t][g*4 + s];
                    if (w > 0.f) {
                        int ee = g*SSS + s;
                        int pos = atomicAdd(&counts[ee], 1);
                        bucket_tok[ee*NT + pos]  = t0 + t;
                        bucket_w[ee*NT + pos]    = w;
                        bucket_slot[ee*NT + pos] = sc & 3;   // slot ordinal
                        ++sc;
                    }
                }
            }
        }
    }
}

// ---------------------------------------------------------------------------
// Expert GEMM (swapped MFMA operands: W as A, X/H as B) so D: row = y-col
// (quad*4+reg -> 4 CONSECUTIVE cols/lane), col = token (lm). XCD-pinned grid.
// Epilogue mode: 2 = fp16 slot-buffer plain stores (no atomics),
//                1 = packed __half2 unsafeAtomicAdd into y-shaped fp16 buf,
//                0 = fp32 atomicAdd into y (round-8 proven behavior).
// ---------------------------------------------------------------------------
__global__ __launch_bounds__(256) void expert_mfma5(
    const float* __restrict__ hidden,
    const float* __restrict__ We1, const float* __restrict__ be1,
    const float* __restrict__ We2, const float* __restrict__ be2,
    const int* __restrict__ bucket_tok, const float* __restrict__ bucket_w,
    const int* __restrict__ bucket_slot,
    const int* __restrict__ counts,
    float* __restrict__ y, __half2* __restrict__ h2buf,
    __half2* __restrict__ sbuf, int mode)
{
    const int e    = blockIdx.x & 31;
    const int tile = blockIdx.x >> 5;
    const int cnt  = counts[e];
    const int r0   = tile * TM;
    if (r0 >= cnt) return;
    const int nrow = min(TM, cnt - r0);
    const int tid  = threadIdx.x;
    const int wave = tid >> 6;
    const int lane = tid & 63;
    const int lm   = lane & 15;
    const int quad = lane >> 4;

    __shared__ short Xp[64 * XC_STRIDE];   // X: [k8][tok][8]
    __shared__ short Hp[32 * XC_STRIDE];   // H: [h8][tok][8]
    __shared__ int   toks[TM];
    __shared__ float tws[TM];
    __shared__ int   tsl[TM];

    if (tid < TM) {
        if (tid < nrow) {
            toks[tid] = bucket_tok[e*NT + r0 + tid];
            tws[tid]  = bucket_w[e*NT + r0 + tid];
            tsl[tid]  = bucket_slot[e*NT + r0 + tid];
        } else { toks[tid] = -1; tws[tid] = 0.f; tsl[tid] = 0; }
    }
    __syncthreads();

    // stage ALL of X (32 tok x 512 k) as bf16, layout [k8][tok][8]
    {
        const int xr = tid >> 3;      // token 0..31
        const int xk = tid & 7;       // k8 subgroup
        const int tk = toks[xr];
        const float* src = hidden + (size_t)(tk < 0 ? 0 : tk)*DD;
        #pragma unroll
        for (int i = 0; i < 8; ++i) {
            const int k8 = xk + 8*i;
            float4 v0 = make_float4(0.f,0.f,0.f,0.f), v1 = v0;
            if (tk >= 0) {
                v0 = *(const float4*)(src + k8*8);
                v1 = *(const float4*)(src + k8*8 + 4);
            }
            U4S8 cv;
            cv.u[0] = pk2(v0.x, v0.y); cv.u[1] = pk2(v0.z, v0.w);
            cv.u[2] = pk2(v1.x, v1.y); cv.u[3] = pk2(v1.z, v1.w);
            *(short8*)(&Xp[k8 * XC_STRIDE + xr * 8]) = cv.s;
        }
    }
    __syncthreads();

    // ---- phase 1 (swapped): D[row=h-col, col=token]; wave owns 64 h-cols ----
    floatx4 acc[2][4];    // [token-half][h-frag]
    #pragma unroll
    for (int tb = 0; tb < 2; ++tb)
        #pragma unroll
        for (int nb = 0; nb < 4; ++nb)
            acc[tb][nb] = (floatx4){0.f, 0.f, 0.f, 0.f};

    const float* W1 = We1 + (size_t)e * DD * DHC;

    for (int i = 0; i < 16; ++i) {
        const int k8 = i*4 + quad;
        short8 x0 = *(const short8*)(&Xp[k8 * XC_STRIDE + lm * 8]);
        short8 x1 = *(const short8*)(&Xp[k8 * XC_STRIDE + (16 + lm) * 8]);
        float wreg[4][8];
        #pragma unroll
        for (int nb = 0; nb < 4; ++nb) {
            const float* s = W1 + (size_t)(k8*8)*DHC + wave*64 + nb*16 + lm;
            #pragma unroll
            for (int j = 0; j < 8; ++j) wreg[nb][j] = s[(size_t)j*DHC];
        }
        #pragma unroll
        for (int nb = 0; nb < 4; ++nb) {
            U4S8 cv;
            cv.u[0] = pk2(wreg[nb][0], wreg[nb][1]);
            cv.u[1] = pk2(wreg[nb][2], wreg[nb][3]);
            cv.u[2] = pk2(wreg[nb][4], wreg[nb][5]);
            cv.u[3] = pk2(wreg[nb][6], wreg[nb][7]);
            acc[0][nb] = mfma16(cv.s, x0, acc[0][nb]);   // W as A-operand
            acc[1][nb] = mfma16(cv.s, x1, acc[1][nb]);
        }
    }

    // gelu -> Hp. Lane owns token (tb*16+lm), h-cols h0..h0+3 -> one b64 write.
    #pragma unroll
    for (int nb = 0; nb < 4; ++nb) {
        const int h0 = wave*64 + nb*16 + quad*4;
        const float4 b1v = *(const float4*)(be1 + e*DHC + h0);
        const int h8  = h0 >> 3;
        const int ofs = (quad & 1) * 4;
        #pragma unroll
        for (int tb = 0; tb < 2; ++tb) {
            const int m = tb*16 + lm;
            unsigned u0 = pk2(gelu_exact(acc[tb][nb][0] + b1v.x),
                              gelu_exact(acc[tb][nb][1] + b1v.y));
            unsigned u1 = pk2(gelu_exact(acc[tb][nb][2] + b1v.z),
                              gelu_exact(acc[tb][nb][3] + b1v.w));
            *(uint2*)(&Hp[h8 * XC_STRIDE + m * 8 + ofs]) = make_uint2(u0, u1);
        }
    }
    __syncthreads();

    // ---- phase 2 (swapped): D[row=y-col, col=token]; wave owns 128 cols ----
    floatx4 c[2][8];
    #pragma unroll
    for (int tb = 0; tb < 2; ++tb)
        #pragma unroll
        for (int nb = 0; nb < 8; ++nb)
            c[tb][nb] = (floatx4){0.f, 0.f, 0.f, 0.f};

    const float* W2 = We2 + (size_t)e * DHC * DD;

    for (int i = 0; i < 8; ++i) {
        const int k8 = i*4 + quad;
        short8 h0 = *(const short8*)(&Hp[k8 * XC_STRIDE + lm * 8]);
        short8 h1 = *(const short8*)(&Hp[k8 * XC_STRIDE + (16 + lm) * 8]);
        #pragma unroll
        for (int half = 0; half < 2; ++half) {
            float wreg[4][8];
            #pragma unroll
            for (int nb4 = 0; nb4 < 4; ++nb4) {
                const int n = wave*128 + (half*4 + nb4)*16 + lm;
                const float* s = W2 + (size_t)(k8*8)*DD + n;
                #pragma unroll
                for (int j = 0; j < 8; ++j) wreg[nb4][j] = s[(size_t)j*DD];
            }
            #pragma unroll
            for (int nb4 = 0; nb4 < 4; ++nb4) {
                const int nb = half*4 + nb4;
                U4S8 cv;
                cv.u[0] = pk2(wreg[nb4][0], wreg[nb4][1]);
                cv.u[1] = pk2(wreg[nb4][2], wreg[nb4][3]);
                cv.u[2] = pk2(wreg[nb4][4], wreg[nb4][5]);
                cv.u[3] = pk2(wreg[nb4][6], wreg[nb4][7]);
                c[0][nb] = mfma16(cv.s, h0, c[0][nb]);
                c[1][nb] = mfma16(cv.s, h1, c[1][nb]);
            }
        }
    }

    // epilogue: lane owns token (tb*16+lm) and 4 consecutive cols per nb.
    #pragma unroll
    for (int tb = 0; tb < 2; ++tb) {
        const int m  = tb*16 + lm;
        const int tk = toks[m];
        if (tk < 0) continue;
        const float w = tws[m];
        const int sl = tsl[m];
        #pragma unroll
        for (int nb = 0; nb < 8; ++nb) {
            const int col0 = wave*128 + nb*16 + quad*4;
            const float4 b2v = *(const float4*)(be2 + e*DD + col0);
            float v0 = w * (c[tb][nb][0] + b2v.x);
            float v1 = w * (c[tb][nb][1] + b2v.y);
            float v2 = w * (c[tb][nb][2] + b2v.z);
            float v3 = w * (c[tb][nb][3] + b2v.w);
            if (mode == 2) {
                // plain 8 B store into slot buffer
                size_t pidx = (((size_t)tk*4 + sl)*DD + col0) >> 1;
                __half2 ha = __floats2half2_rn(v0, v1);
                __half2 hb = __floats2half2_rn(v2, v3);
                union { __half2 h[2]; uint2 u; } pk; pk.h[0] = ha; pk.h[1] = hb;
                *(uint2*)(&sbuf[pidx]) = pk.u;
            } else if (mode == 1) {
                size_t pidx = ((size_t)tk*DD + col0) >> 1;
                unsafeAtomicAdd(&h2buf[pidx],     __floats2half2_rn(v0, v1));
                unsafeAtomicAdd(&h2buf[pidx + 1], __floats2half2_rn(v2, v3));
            } else {
                float* yp = y + (size_t)tk*DD + col0;
                atomicAdd(yp + 0, v0);
                atomicAdd(yp + 1, v1);
                atomicAdd(yp + 2, v2);
                atomicAdd(yp + 3, v3);
            }
        }
    }
}

// mode 2: y[t][c] = sum_s sbuf[t][s][c]
__global__ __launch_bounds__(256) void combine_slots(
    const __half2* __restrict__ sbuf, float* __restrict__ y)
{
    int i = blockIdx.x * 256 + threadIdx.x;   // over NT*256 col-pairs
    int t = i >> 8, cp = i & 255;
    float sx = 0.f, sy = 0.f;
    #pragma unroll
    for (int s = 0; s < 4; ++s) {
        float2 f = __half22float2(sbuf[(((size_t)t*4 + s) << 8) + cp]);
        sx += f.x; sy += f.y;
    }
    *(float2*)(y + (size_t)i*2) = make_float2(sx, sy);
}

// mode 1: fp16 accum -> fp32 y
__global__ __launch_bounds__(256) void h2_to_f32(
    const __half2* __restrict__ h2buf, float* __restrict__ y)
{
    int i = blockIdx.x * 256 + threadIdx.x;      // over NT*256 pairs
    float2 f = __half22float2(h2buf[i]);
    *(float2*)(y + (size_t)i*2) = f;
}

extern "C" void kernel_launch(void* const* d_in, const int* in_sizes, int n_in,
                              void* d_out, int out_size, void* d_ws, size_t ws_size,
                              hipStream_t stream) {
    const float* hidden = (const float*)d_in[0];
    const float* feat   = (const float*)d_in[1];
    // d_in[2] = valid_mask (unused)
    const float* Wr1    = (const float*)d_in[3];
    const float* br1    = (const float*)d_in[4];
    const float* Wr2    = (const float*)d_in[5];
    const float* br2    = (const float*)d_in[6];
    const float* Wfe    = (const float*)d_in[7];
    const float* bfe    = (const float*)d_in[8];
    const float* Win_h  = (const float*)d_in[9];
    const float* Win_f  = (const float*)d_in[10];
    const float* bin_b  = (const float*)d_in[11];
    const float* We1    = (const float*)d_in[12];
    const float* be1    = (const float*)d_in[13];
    const float* We2    = (const float*)d_in[14];
    const float* be2    = (const float*)d_in[15];
    float* y = (float*)d_out;

    char* ws0 = (char*)d_ws;
    char* ws  = ws0;
    int*   bucket_tok  = (int*)ws;    ws += (size_t)EEC*NT*sizeof(int);    // 512 KB
    float* bucket_w    = (float*)ws;  ws += (size_t)EEC*NT*sizeof(float);  // 512 KB
    int*   bucket_slot = (int*)ws;    ws += (size_t)EEC*NT*sizeof(int);    // 512 KB
    int*   counts      = (int*)ws;    ws += 256;
    float* WinT        = (float*)ws;  ws += (size_t)DD*EEC*sizeof(float);  // 64 KB
    float* M2          = (float*)ws;  ws += 512;
    float* c2b         = (float*)ws;  ws += 128;
    char*  bigbuf      = ws;          // sbuf (16 MB) or h2buf (4 MB), aliased
    const size_t base = (size_t)(ws - ws0);
    const size_t need2 = base + (size_t)NT*4*DD*sizeof(__half);   // ~17.7 MB
    const size_t need1 = base + (size_t)NT*DD*sizeof(__half);     // ~5.7 MB
    const int mode = (ws_size >= need2) ? 2 : (ws_size >= need1) ? 1 : 0;

    __half2* sbuf  = (__half2*)bigbuf;
    __half2* h2buf = (__half2*)bigbuf;

    // zero target and floats-per-token for routing's zeroing pass
    float* zbuf = (mode == 2) ? (float*)sbuf : (mode == 1) ? (float*)h2buf : y;
    int    zn   = (mode == 2) ? 1024 : (mode == 1) ? 256 : 512;

    (void)hipMemsetAsync(counts, 0, EEC*sizeof(int), stream);

    prep_kernel<<<65, 256, 0, stream>>>(Win_h, Win_f, Wfe, bfe, bin_b,
                                        WinT, M2, c2b);

    fused_route2<<<NT/TR, 256, 0, stream>>>(hidden, feat, Wr1, br1, Wr2, br2,
                                            WinT, M2, c2b,
                                            bucket_tok, bucket_w, bucket_slot,
                                            counts, zbuf, zn);

    expert_mfma5<<<(NT/TM)*EEC, 256, 0, stream>>>(hidden, We1, be1, We2, be2,
                                                  bucket_tok, bucket_w, bucket_slot,
                                                  counts, y, h2buf, sbuf, mode);

    if (mode == 2) {
        combine_slots<<<(NT*256)/256, 256, 0, stream>>>(sbuf, y);
    } else if (mode == 1) {
        h2_to_f32<<<(NT*256)/256, 256, 0, stream>>>(h2buf, y);
    }
}